// Round 6
// baseline (446.358 us; speedup 1.0000x reference)
//
#include <hip/hip_runtime.h>
#include <hip/hip_bf16.h>
#include <cstdint>

typedef _Float16 half8 __attribute__((ext_vector_type(8)));
typedef float floatx4 __attribute__((ext_vector_type(4)));

#define KPC 2048
// HW_REG_XCC_ID (id=20, offset=0, size=4)  [measured: learn_hip m09; R4-verified]
#define XCC_GETREG ((3 << 11) | 20)

// ---------------------------------------------------------------------------
// Kernel 0: rwbT[n][k] = dot(rel_features[k,:], W[n,:]) + b[n]  (fp16, [128][KPC])
// ---------------------------------------------------------------------------
__global__ void rwb_kernel(const float* __restrict__ rel, const float* __restrict__ W,
                           const float* __restrict__ b, _Float16* __restrict__ rwbT,
                           int R) {
    const int k = blockIdx.x;
    const int n = threadIdx.x;
    __shared__ float relk[128];
    if (k < R) relk[n] = rel[(size_t)k * 128 + n];
    __syncthreads();
    float acc = 0.f;
    if (k < R) {
        const float4* w4 = reinterpret_cast<const float4*>(W + (size_t)n * 128);
        const float4* r4 = reinterpret_cast<const float4*>(relk);
#pragma unroll
        for (int i = 0; i < 32; ++i) {
            float4 a = r4[i], w = w4[i];
            acc += a.x * w.x + a.y * w.y + a.z * w.z + a.w * w.w;
        }
        acc += b[n];
    }
    rwbT[(size_t)n * KPC + k] = (_Float16)acc;
}

// ---------------------------------------------------------------------------
// Kernel 1: L2-resident sliced scatter. 8 entity-slices (one per XCD) x 2
// relation-half passes -> active S region 2048x1024 fp16 = 4 MB = one L2.
// pk-f16 atomics at L2 scope (no sc bits); inputs streamed non-temporally so
// they don't evict the slice. Chunk claiming per (xcd,pass) via device
// counters covers every fact exactly once per slice.
// ---------------------------------------------------------------------------
__global__ __launch_bounds__(256) void scatter2_kernel(
    const int* __restrict__ heads, const int* __restrict__ tails,
    const int* __restrict__ rels, const float* __restrict__ val,
    _Float16* __restrict__ S, int* __restrict__ counters,
    int E, int nchunk, int chunk, int slice_shift) {
    __shared__ int s_chunk;
    const int xcd = __builtin_amdgcn_s_getreg(XCC_GETREG) & 7;
    for (int pass = 0; pass < 2; ++pass) {
        for (;;) {
            __syncthreads();
            if (threadIdx.x == 0) s_chunk = atomicAdd(&counters[xcd * 2 + pass], 1);
            __syncthreads();
            const int c = s_chunk;
            if (c >= nchunk) break;
            const int base = c * chunk;
            const int end = min(base + chunk, E);
            for (int i = base + (int)threadIdx.x; i < end; i += 256) {
                const int tv = __builtin_nontemporal_load(tails + i);
                const int hv = __builtin_nontemporal_load(heads + i);
                const int r  = __builtin_nontemporal_load(rels + i);
                if ((r >> 10) != pass) continue;
                const bool tok = (tv >> slice_shift) == xcd;
                const bool hok = (hv >> slice_shift) == xcd;
                if (!tok && !hok) continue;
                const float w = __builtin_nontemporal_load(val + i);
                const unsigned short hbits =
                    __builtin_bit_cast(unsigned short, (_Float16)w);
                const unsigned pk = (r & 1) ? ((unsigned)hbits << 16) : (unsigned)hbits;
                const size_t c2 = (size_t)(r >> 1);
                if (tok) {
                    uint64_t addr = (uint64_t)(S + (size_t)tv * KPC) + c2 * 4;
                    asm volatile("global_atomic_pk_add_f16 %0, %1, off"
                                 :: "v"(addr), "v"(pk) : "memory");
                }
                if (hok) {
                    uint64_t addr = (uint64_t)(S + (size_t)hv * KPC) + c2 * 4;
                    asm volatile("global_atomic_pk_add_f16 %0, %1, off"
                                 :: "v"(addr), "v"(pk) : "memory");
                }
            }
        }
    }
}

// ---------------------------------------------------------------------------
// Kernel 2: split-K direct-fragment GEMM (no LDS, no barriers). 4 K-chunks of
// 512 -> 4000 independent waves (~16/CU). Wave u: rows [mt*16, mt*16+16),
// K-chunk kc; A fp16 from S, B from L2-hot rwbT; partial C to P[kc].
// ---------------------------------------------------------------------------
__global__ __launch_bounds__(256) void gemmsk_kernel(
    const _Float16* __restrict__ S, const _Float16* __restrict__ rwbT,
    float* __restrict__ P, int MTILES) {
    const int wave = threadIdx.x >> 6, lane = threadIdx.x & 63;
    const int u = blockIdx.x * 4 + wave;
    const int mt = u % MTILES;
    const int kc = u / MTILES;
    const int m0 = mt * 16;
    const int quad = lane >> 4, fr = lane & 15;

    const _Float16* ap = S + (size_t)(m0 + fr) * KPC + kc * 512 + quad * 8;
    const _Float16* bp = rwbT + (size_t)fr * KPC + kc * 512 + quad * 8;

    floatx4 acc[8] = {};
#pragma unroll 2
    for (int k0 = 0; k0 < 512; k0 += 32) {
        const half8 af = *reinterpret_cast<const half8*>(ap + k0);
#pragma unroll
        for (int ni = 0; ni < 8; ++ni) {
            const half8 bf = *reinterpret_cast<const half8*>(bp + (size_t)ni * 16 * KPC + k0);
            acc[ni] = __builtin_amdgcn_mfma_f32_16x16x32_f16(af, bf, acc[ni], 0, 0, 0);
        }
    }

    // C/D layout: col = lane&15, row = quad*4 + g  [m89-verified]
    float* po = P + (size_t)kc * MTILES * 16 * 128 + (size_t)m0 * 128;
#pragma unroll
    for (int ni = 0; ni < 8; ++ni)
#pragma unroll
        for (int g = 0; g < 4; ++g)
            po[(quad * 4 + g) * 128 + ni * 16 + fr] = acc[ni][g];
}

// ---------------------------------------------------------------------------
// Kernel 3: reduce 4 partials + relu. Coalesced float4.
// ---------------------------------------------------------------------------
__global__ void reduceK_kernel(const float4* __restrict__ P, float4* __restrict__ out,
                               int n4) {
    const int i = blockIdx.x * blockDim.x + threadIdx.x;
    if (i >= n4) return;
    const float4 a = P[i];
    const float4 b = P[i + (size_t)n4];
    const float4 c = P[i + (size_t)2 * n4];
    const float4 d = P[i + (size_t)3 * n4];
    float4 r;
    r.x = fmaxf(a.x + b.x + c.x + d.x, 0.f);
    r.y = fmaxf(a.y + b.y + c.y + d.y, 0.f);
    r.z = fmaxf(a.z + b.z + c.z + d.z, 0.f);
    r.w = fmaxf(a.w + b.w + c.w + d.w, 0.f);
    out[i] = r;
}

// ---------------------------------------------------------------------------
// Fallback path (only if assumptions violated): direct vector scatter.
// ---------------------------------------------------------------------------
__global__ void rwb_f32_kernel(const float* __restrict__ rel, const float* __restrict__ W,
                               const float* __restrict__ b, float* __restrict__ rwb, int R) {
    const int k = blockIdx.x;
    const int n = threadIdx.x;
    __shared__ float relk[128];
    relk[n] = rel[(size_t)k * 128 + n];
    __syncthreads();
    const float4* w4 = reinterpret_cast<const float4*>(W + (size_t)n * 128);
    const float4* r4 = reinterpret_cast<const float4*>(relk);
    float acc = 0.f;
#pragma unroll
    for (int i = 0; i < 32; ++i) {
        float4 a = r4[i], w = w4[i];
        acc += a.x * w.x + a.y * w.y + a.z * w.z + a.w * w.w;
    }
    rwb[(size_t)k * 128 + n] = acc + b[n];
}

__global__ void scatter_vec_kernel(const int* __restrict__ heads, const int* __restrict__ tails,
                                   const int* __restrict__ rels, const float* __restrict__ val,
                                   const float* __restrict__ rwb, float* __restrict__ out,
                                   long long nitems) {
    const long long i = (long long)blockIdx.x * blockDim.x + threadIdx.x;
    if (i >= nitems) return;
    const int e = (int)(i >> 5);
    const int c = (int)(i & 31) * 4;
    const float v = val[e];
    float4 rw = *reinterpret_cast<const float4*>(rwb + (size_t)rels[e] * 128 + c);
    float* pt = out + (size_t)tails[e] * 128 + c;
    float* ph = out + (size_t)heads[e] * 128 + c;
    unsafeAtomicAdd(pt + 0, v * rw.x); unsafeAtomicAdd(pt + 1, v * rw.y);
    unsafeAtomicAdd(pt + 2, v * rw.z); unsafeAtomicAdd(pt + 3, v * rw.w);
    unsafeAtomicAdd(ph + 0, v * rw.x); unsafeAtomicAdd(ph + 1, v * rw.y);
    unsafeAtomicAdd(ph + 2, v * rw.z); unsafeAtomicAdd(ph + 3, v * rw.w);
}

__global__ void relu_kernel(float* __restrict__ out, int n4) {
    const int i = blockIdx.x * blockDim.x + threadIdx.x;
    if (i >= n4) return;
    float4* p = reinterpret_cast<float4*>(out) + i;
    float4 v = *p;
    v.x = fmaxf(v.x, 0.f); v.y = fmaxf(v.y, 0.f);
    v.z = fmaxf(v.z, 0.f); v.w = fmaxf(v.w, 0.f);
    *p = v;
}

// ---------------------------------------------------------------------------
extern "C" void kernel_launch(void* const* d_in, const int* in_sizes, int n_in,
                              void* d_out, int out_size, void* d_ws, size_t ws_size,
                              hipStream_t stream) {
    // inputs: 0 local_entity [B*M], 1 heads [E], 2 tails [E], 3 rels [E],
    //         4 val [E], 5 rel_features [R*D], 6 W [D*D], 7 b [D]
    const int* heads = (const int*)d_in[1];
    const int* tails = (const int*)d_in[2];
    const int* rels  = (const int*)d_in[3];
    const float* val  = (const float*)d_in[4];
    const float* relf = (const float*)d_in[5];
    const float* W    = (const float*)d_in[6];
    const float* b    = (const float*)d_in[7];
    float* out = (float*)d_out;

    const int NUMENT = in_sizes[0];          // 16000
    const int E      = in_sizes[1];          // 2,000,000
    const int D      = in_sizes[7];          // 128
    const int R      = in_sizes[5] / D;      // 2000

    // slice_shift: smallest s with (NUMENT-1)>>s <= 7
    int slice_shift = 8;
    while (((NUMENT - 1) >> slice_shift) > 7) ++slice_shift;

    // workspace: [rwbT 512K][counters 256B][S fp16 ~65.5MB][P fp32 ~32.8MB]
    const size_t rwbT_bytes = (size_t)128 * KPC * sizeof(_Float16);
    const size_t cnt_off    = (rwbT_bytes + 255) & ~(size_t)255;
    const size_t S_off      = cnt_off + 256;
    const size_t S_bytes    = (size_t)NUMENT * KPC * sizeof(_Float16);
    const size_t P_off      = (S_off + S_bytes + 255) & ~(size_t)255;
    const size_t P_bytes    = (size_t)4 * NUMENT * 128 * sizeof(float);
    const size_t total      = P_off + P_bytes;

    const bool fast = (D == 128) && (R <= KPC) && (NUMENT % 16 == 0) &&
                      (ws_size >= total);

    if (fast) {
        _Float16* rwbT = (_Float16*)d_ws;
        int* counters  = (int*)((char*)d_ws + cnt_off);
        _Float16* S    = (_Float16*)((char*)d_ws + S_off);
        float* P       = (float*)((char*)d_ws + P_off);

        const int chunk  = 8192;
        const int nchunk = (E + chunk - 1) / chunk;
        const int MTILES = NUMENT / 16;

        hipMemsetAsync((char*)d_ws + cnt_off, 0, 256 + S_bytes, stream);
        rwb_kernel<<<KPC, 128, 0, stream>>>(relf, W, b, rwbT, R);
        scatter2_kernel<<<2048, 256, 0, stream>>>(heads, tails, rels, val,
                                                  S, counters, E, nchunk, chunk,
                                                  slice_shift);
        gemmsk_kernel<<<MTILES, 256, 0, stream>>>(S, rwbT, P, MTILES);
        const int n4 = NUMENT * 128 / 4;
        reduceK_kernel<<<(n4 + 255) / 256, 256, 0, stream>>>(
            (const float4*)P, (float4*)out, n4);
    } else {
        // fallback: accumulate directly into out
        float* rwb = (float*)d_ws;
        hipMemsetAsync(out, 0, (size_t)out_size * sizeof(float), stream);
        rwb_f32_kernel<<<R, 128, 0, stream>>>(relf, W, b, rwb, R);
        const long long items = (long long)E * 32;
        scatter_vec_kernel<<<(unsigned)((items + 255) / 256), 256, 0, stream>>>(
            heads, tails, rels, val, rwb, out, items);
        relu_kernel<<<(out_size / 4 + 255) / 256, 256, 0, stream>>>(out, out_size / 4);
    }
}

// Round 7
// 345.632 us; speedup vs baseline: 1.2914x; 1.2914x over previous
//
#include <hip/hip_runtime.h>
#include <hip/hip_bf16.h>
#include <cstdint>

typedef unsigned short ushort_t;
typedef _Float16 half8 __attribute__((ext_vector_type(8)));
typedef _Float16 half2v __attribute__((ext_vector_type(2)));
typedef float floatx4 __attribute__((ext_vector_type(4)));

#define KPC 2048
#define BSTRIDE 136   // 128 + 8-half pad: row bank shift 4, 2-way on frag reads = free

// ---------------------------------------------------------------------------
// Kernel 0: rwbT[n][k] = dot(rel_features[k,:], W[n,:]) + b[n]  (fp16, [128][KPC])
// k >= R rows are zero (pad K contributes nothing).
// ---------------------------------------------------------------------------
__global__ void rwb_kernel(const float* __restrict__ rel, const float* __restrict__ W,
                           const float* __restrict__ b, _Float16* __restrict__ rwbT,
                           int R) {
    const int k = blockIdx.x;
    const int n = threadIdx.x;
    __shared__ float relk[128];
    if (k < R) relk[n] = rel[(size_t)k * 128 + n];
    __syncthreads();
    float acc = 0.f;
    if (k < R) {
        const float4* w4 = reinterpret_cast<const float4*>(W + (size_t)n * 128);
        const float4* r4 = reinterpret_cast<const float4*>(relk);
#pragma unroll
        for (int i = 0; i < 32; ++i) {
            float4 a = r4[i], w = w4[i];
            acc += a.x * w.x + a.y * w.y + a.z * w.z + a.w * w.w;
        }
        acc += b[n];
    }
    rwbT[(size_t)n * KPC + k] = (_Float16)acc;
}

// ---------------------------------------------------------------------------
// Kernel 1: S[v][r] += val for v in {tail, head}. fp16 packed atomics, device
// scope. R1-proven: 194 us — at the 4M x 32-B write-through wall.
// ---------------------------------------------------------------------------
__global__ void scatter_kernel(const int* __restrict__ heads, const int* __restrict__ tails,
                               const int* __restrict__ rels, const float* __restrict__ val,
                               half2v* __restrict__ S2, int E) {
    const int i = blockIdx.x * blockDim.x + threadIdx.x;
    if (i >= E) return;
    const int r = rels[i];
    const _Float16 hv = (_Float16)val[i];
    half2v add;
    add[0] = (r & 1) ? (_Float16)0.f : hv;
    add[1] = (r & 1) ? hv : (_Float16)0.f;
    const int c = r >> 1;
    __builtin_amdgcn_global_atomic_fadd_v2f16(&S2[(size_t)tails[i] * (KPC / 2) + c], add);
    __builtin_amdgcn_global_atomic_fadd_v2f16(&S2[(size_t)heads[i] * (KPC / 2) + c], add);
}

// ---------------------------------------------------------------------------
// Kernel 2: out = relu(S @ RWB^T-layout)  — fp16 MFMA GEMM, B LDS-staged.
// Tile: 64M x 128N, BK=128. 4 waves: (wm,wn) in 2x2, wave = 32M x 64N,
// acc[2][4]. B staged once per chunk into Bs[128][136] (34 KB, shared by all
// waves -> B L2 traffic 250x512KB = 128 MB, not 8.2 GB). A-frags direct from
// global (16-B loads, 64-B granule/row). M=16000 = 250*64 exact, no bounds.
// ---------------------------------------------------------------------------
__global__ __launch_bounds__(256, 2) void gemm_kernel(
    const _Float16* __restrict__ S, const _Float16* __restrict__ rwbT,
    float* __restrict__ out) {
    __shared__ _Float16 Bs[128 * BSTRIDE];   // ~34 KB

    const int t = threadIdx.x;
    const int lane = t & 63;
    const int wave = t >> 6;
    const int wm = wave >> 1;          // 0/1 -> m offset 0/32
    const int wn = wave & 1;           // 0/1 -> n offset 0/64
    const int quad = lane >> 4;
    const int fr = lane & 15;
    const int m0 = blockIdx.x * 64;

    // B staging assignment: row n = t>>1, k-segment (t&1)*64
    const int sb_n = t >> 1;
    const int sb_k = (t & 1) * 64;
    const _Float16* bsrc = rwbT + (size_t)sb_n * KPC + sb_k;
    _Float16* bdst = &Bs[sb_n * BSTRIDE + sb_k];

    // A pointers: rows m0 + wm*32 + mi*16 + fr, k-offset quad*8
    const _Float16* ap0 = S + (size_t)(m0 + wm * 32 + fr) * KPC + quad * 8;
    const _Float16* ap1 = ap0 + (size_t)16 * KPC;

    floatx4 acc[2][4] = {};

    for (int kb = 0; kb < KPC; kb += 128) {
        // stage B chunk: 128 B per thread (8 x 16 B)
#pragma unroll
        for (int j = 0; j < 8; ++j)
            *reinterpret_cast<half8*>(bdst + j * 8) =
                *reinterpret_cast<const half8*>(bsrc + kb + j * 8);
        __syncthreads();

#pragma unroll
        for (int k0 = 0; k0 < 128; k0 += 32) {
            const half8 af0 = *reinterpret_cast<const half8*>(ap0 + kb + k0);
            const half8 af1 = *reinterpret_cast<const half8*>(ap1 + kb + k0);
            half8 bfv[4];
#pragma unroll
            for (int ni = 0; ni < 4; ++ni)
                bfv[ni] = *reinterpret_cast<const half8*>(
                    &Bs[(wn * 64 + ni * 16 + fr) * BSTRIDE + k0 + quad * 8]);
#pragma unroll
            for (int ni = 0; ni < 4; ++ni) {
                acc[0][ni] = __builtin_amdgcn_mfma_f32_16x16x32_f16(af0, bfv[ni], acc[0][ni], 0, 0, 0);
                acc[1][ni] = __builtin_amdgcn_mfma_f32_16x16x32_f16(af1, bfv[ni], acc[1][ni], 0, 0, 0);
            }
        }
        __syncthreads();
    }

    // epilogue: C/D layout col=lane&15, row=quad*4+g  [m89-verified]; relu
#pragma unroll
    for (int mi = 0; mi < 2; ++mi)
#pragma unroll
        for (int ni = 0; ni < 4; ++ni)
#pragma unroll
            for (int g = 0; g < 4; ++g) {
                const int m = m0 + wm * 32 + mi * 16 + quad * 4 + g;
                const int n = wn * 64 + ni * 16 + fr;
                out[(size_t)m * 128 + n] = fmaxf(acc[mi][ni][g], 0.f);
            }
}

// ---------------------------------------------------------------------------
// Fallback path (only if assumptions violated): direct vector scatter.
// ---------------------------------------------------------------------------
__global__ void rwb_f32_kernel(const float* __restrict__ rel, const float* __restrict__ W,
                               const float* __restrict__ b, float* __restrict__ rwb, int R) {
    const int k = blockIdx.x;
    const int n = threadIdx.x;
    __shared__ float relk[128];
    relk[n] = rel[(size_t)k * 128 + n];
    __syncthreads();
    const float4* w4 = reinterpret_cast<const float4*>(W + (size_t)n * 128);
    const float4* r4 = reinterpret_cast<const float4*>(relk);
    float acc = 0.f;
#pragma unroll
    for (int i = 0; i < 32; ++i) {
        float4 a = r4[i], w = w4[i];
        acc += a.x * w.x + a.y * w.y + a.z * w.z + a.w * w.w;
    }
    rwb[(size_t)k * 128 + n] = acc + b[n];
}

__global__ void scatter_vec_kernel(const int* __restrict__ heads, const int* __restrict__ tails,
                                   const int* __restrict__ rels, const float* __restrict__ val,
                                   const float* __restrict__ rwb, float* __restrict__ out,
                                   long long nitems) {
    const long long i = (long long)blockIdx.x * blockDim.x + threadIdx.x;
    if (i >= nitems) return;
    const int e = (int)(i >> 5);
    const int c = (int)(i & 31) * 4;
    const float v = val[e];
    float4 rw = *reinterpret_cast<const float4*>(rwb + (size_t)rels[e] * 128 + c);
    float* pt = out + (size_t)tails[e] * 128 + c;
    float* ph = out + (size_t)heads[e] * 128 + c;
    unsafeAtomicAdd(pt + 0, v * rw.x); unsafeAtomicAdd(pt + 1, v * rw.y);
    unsafeAtomicAdd(pt + 2, v * rw.z); unsafeAtomicAdd(pt + 3, v * rw.w);
    unsafeAtomicAdd(ph + 0, v * rw.x); unsafeAtomicAdd(ph + 1, v * rw.y);
    unsafeAtomicAdd(ph + 2, v * rw.z); unsafeAtomicAdd(ph + 3, v * rw.w);
}

__global__ void relu_kernel(float* __restrict__ out, int n4) {
    const int i = blockIdx.x * blockDim.x + threadIdx.x;
    if (i >= n4) return;
    float4* p = reinterpret_cast<float4*>(out) + i;
    float4 v = *p;
    v.x = fmaxf(v.x, 0.f); v.y = fmaxf(v.y, 0.f);
    v.z = fmaxf(v.z, 0.f); v.w = fmaxf(v.w, 0.f);
    *p = v;
}

// ---------------------------------------------------------------------------
extern "C" void kernel_launch(void* const* d_in, const int* in_sizes, int n_in,
                              void* d_out, int out_size, void* d_ws, size_t ws_size,
                              hipStream_t stream) {
    // inputs: 0 local_entity [B*M], 1 heads [E], 2 tails [E], 3 rels [E],
    //         4 val [E], 5 rel_features [R*D], 6 W [D*D], 7 b [D]
    const int* heads = (const int*)d_in[1];
    const int* tails = (const int*)d_in[2];
    const int* rels  = (const int*)d_in[3];
    const float* val  = (const float*)d_in[4];
    const float* relf = (const float*)d_in[5];
    const float* W    = (const float*)d_in[6];
    const float* b    = (const float*)d_in[7];
    float* out = (float*)d_out;

    const int NUMENT = in_sizes[0];          // 16000
    const int E      = in_sizes[1];          // 2,000,000
    const int D      = in_sizes[7];          // 128
    const int R      = in_sizes[5] / D;      // 2000

    // workspace: [rwbT 512K][S fp16 ~65.5MB]
    const size_t rwbT_bytes = (size_t)128 * KPC * sizeof(_Float16);
    const size_t S_off      = (rwbT_bytes + 255) & ~(size_t)255;
    const size_t S_bytes    = (size_t)NUMENT * KPC * sizeof(_Float16);
    const size_t total      = S_off + S_bytes;

    const bool fast = (D == 128) && (R <= KPC) && (NUMENT % 64 == 0) &&
                      (ws_size >= total);

    if (fast) {
        _Float16* rwbT = (_Float16*)d_ws;
        half2v* S2     = (half2v*)((char*)d_ws + S_off);

        hipMemsetAsync(S2, 0, S_bytes, stream);
        rwb_kernel<<<KPC, 128, 0, stream>>>(relf, W, b, rwbT, R);
        scatter_kernel<<<(E + 255) / 256, 256, 0, stream>>>(heads, tails, rels, val, S2, E);
        gemm_kernel<<<NUMENT / 64, 256, 0, stream>>>(
            (const _Float16*)S2, rwbT, out);
    } else {
        // fallback: accumulate directly into out
        float* rwb = (float*)d_ws;
        hipMemsetAsync(out, 0, (size_t)out_size * sizeof(float), stream);
        rwb_f32_kernel<<<R, 128, 0, stream>>>(relf, W, b, rwb, R);
        const long long items = (long long)E * 32;
        scatter_vec_kernel<<<(unsigned)((items + 255) / 256), 256, 0, stream>>>(
            heads, tails, rels, val, rwb, out, items);
        relu_kernel<<<(out_size / 4 + 255) / 256, 256, 0, stream>>>(out, out_size / 4);
    }
}